// Round 8
// baseline (607.500 us; speedup 1.0000x reference)
//
#include <hip/hip_runtime.h>
#include <hip/hip_bf16.h>
#include <cstddef>
#include <cstdint>

#define NBLK(n, b) (((n) + (b) - 1) / (b))

typedef __attribute__((ext_vector_type(8))) short short8;
typedef __attribute__((ext_vector_type(4))) float f32x4;

__device__ inline unsigned short f2bf(float f) {
  union { float f; unsigned u; } v; v.f = f;
  unsigned u = v.u;
  u += 0x7FFFu + ((u >> 16) & 1u);  // RNE
  return (unsigned short)(u >> 16);
}
__device__ inline float bflo(unsigned u) { union { unsigned u; float f; } v; v.u = u << 16; return v.f; }
__device__ inline float bfhi(unsigned u) { union { unsigned u; float f; } v; v.u = u & 0xFFFF0000u; return v.f; }

// CSR bucket sort: buckets of 512 nodes; node ids < 2^17 (N=100K).
// key = src | (localDst << 17) fits u32. Fixed-capacity padded buckets.
#define BSHIFT 9
#define BSIZE 512
#define CAPSHIFT 14
#define CAP 16384
#define ECHUNK 4096

// ---------------- fused setup: cast x, prep W, scatter edges into buckets ----------------
__global__ __launch_bounds__(256) void k_setup(
    const float* __restrict__ x, unsigned* __restrict__ xb, int N,
    const float* __restrict__ W1l, const float* __restrict__ W1r, unsigned short* __restrict__ Wb1,
    const float* __restrict__ W2l, const float* __restrict__ W2r, unsigned short* __restrict__ Wb2,
    const float* __restrict__ W3l, const float* __restrict__ W3r, unsigned short* __restrict__ Wb3,
    const void* __restrict__ edges, int* __restrict__ bucketCursor,
    unsigned* __restrict__ bucketed, int E, int NB) {
  __shared__ int h[1024];
  __shared__ int base2[1024];
  int t = threadIdx.x;
  int b = blockIdx.x;
  int gCast = (N * 64 + 255) >> 8;
  if (b < gCast) {
    int i = b * 256 + t;
    if (i < N * 64) {
      float2 v = *(const float2*)(x + (size_t)i * 2);
      xb[i] = (unsigned)f2bf(v.x) | ((unsigned)f2bf(v.y) << 16);
    }
    return;
  }
  b -= gCast;
  if (b < 320) {
    int ii = b * 256 + t;
    const float *Wl, *Wr; unsigned short* Wb;
    if (ii < 128 * 256) { Wl = W1l; Wr = W1r; Wb = Wb1; }
    else if (ii < 256 * 256) { Wl = W2l; Wr = W2r; Wb = Wb2; ii -= 128 * 256; }
    else { Wl = W3l; Wr = W3r; Wb = Wb3; ii -= 256 * 256; }
    int nrow = ii >> 8, k = ii & 255;
    float v = (k < 128) ? Wr[nrow * 128 + k] : Wl[nrow * 128 + (k - 128)];
    Wb[ii] = f2bf(v);
    return;
  }
  b -= 320;

  // ---- edge scatter ----
  const unsigned* e32 = (const unsigned*)edges;
  int is64 = 1;
#pragma unroll
  for (int i = 0; i < 16; ++i)
    if (e32[2 * i + 1] != 0u) is64 = 0;

  for (int i = t; i < NB; i += 256) h[i] = 0;
  __syncthreads();
  int base_e = b * ECHUNK;
  unsigned key[16];
  int bkt[16];
#pragma unroll
  for (int k = 0; k < 16; ++k) {
    int e = base_e + k * 256 + t;
    bkt[k] = -1;
    if (e < E) {
      int s, d;
      if (is64) {
        s = (int)((const long long*)edges)[e];
        d = (int)((const long long*)edges)[(size_t)E + e];
      } else {
        s = ((const int*)edges)[e];
        d = ((const int*)edges)[(size_t)E + e];
      }
      bkt[k] = d >> BSHIFT;
      key[k] = (unsigned)s | ((unsigned)(d & (BSIZE - 1)) << 17);
      atomicAdd(&h[bkt[k]], 1);
    }
  }
  __syncthreads();
  for (int i = t; i < NB; i += 256) {
    int c = h[i];
    base2[i] = c ? atomicAdd(&bucketCursor[i], c) : 0;
    h[i] = 0;
  }
  __syncthreads();
#pragma unroll
  for (int k = 0; k < 16; ++k) {
    if (bkt[k] >= 0) {
      int r = atomicAdd(&h[bkt[k]], 1);
      int pos = base2[bkt[k]] + r;
      if (pos < CAP)
        bucketed[((size_t)bkt[k] << CAPSHIFT) + pos] = key[k];
    }
  }
}

// ---------------- per-bucket CSR: rowStart + deg + srcSorted (padded layout) ----------------
__global__ __launch_bounds__(256) void k_csr(const unsigned* __restrict__ bucketed,
                                             const int* __restrict__ bucketCursor,
                                             int* __restrict__ rowStart, int* __restrict__ deg,
                                             int* __restrict__ srcSorted, int N, int NB) {
  __shared__ int h[512];
  __shared__ int excl[512];
  __shared__ int sd[256];
  int b = blockIdx.x;
  int t = threadIdx.x;
  int nodeBase = b << BSHIFT;
  int nNode = min(BSIZE, N - nodeBase);
  int cnt = min(bucketCursor[b], CAP);
  size_t s0 = (size_t)b << CAPSHIFT;
  h[t * 2] = 0; h[t * 2 + 1] = 0;
  __syncthreads();
  for (int i = t; i < cnt; i += 256) {
    int ld = bucketed[s0 + i] >> 17;
    atomicAdd(&h[ld], 1);
  }
  __syncthreads();
  int a0 = h[t * 2], a1 = h[t * 2 + 1];
  int s = a0 + a1;
  sd[t] = s;
  __syncthreads();
  for (int off = 1; off < 256; off <<= 1) {
    int xv = (t >= off) ? sd[t - off] : 0;
    __syncthreads();
    sd[t] += xv;
    __syncthreads();
  }
  int run = sd[t] - s;
  excl[t * 2] = run;
  excl[t * 2 + 1] = run + a0;
  if (t * 2 < nNode) {
    rowStart[nodeBase + t * 2] = (int)s0 + run;
    deg[nodeBase + t * 2] = a0;
  }
  if (t * 2 + 1 < nNode) {
    rowStart[nodeBase + t * 2 + 1] = (int)s0 + run + a0;
    deg[nodeBase + t * 2 + 1] = a1;
  }
  h[t * 2] = 0; h[t * 2 + 1] = 0;
  __syncthreads();
  for (int i = t; i < cnt; i += 256) {
    unsigned u = bucketed[s0 + i];
    int ld = u >> 17;
    int r = atomicAdd(&h[ld], 1);
    srcSorted[s0 + excl[ld] + r] = (int)(u & 0x1FFFFu);
  }
}

// ---------------- fused aggregate + SAGE GEMM (layers 1-2, H=128) ----------------
// Phase A: 4 waves x 32 nodes: mean over in-neighbors -> LDS (bf16, stride-68
// uints for 2-way-free banking). Phase B: MFMA GEMM, K=256 concat; self
// fragments from global, mean fragments from LDS.
template <bool RELU>
__global__ __launch_bounds__(256, 3) void k_fused128(
    const unsigned* __restrict__ in,          // rows [n][64] (bf16x2) = self = gather src
    const int* __restrict__ rowStart, const int* __restrict__ deg,
    const int* __restrict__ srcs,
    const unsigned short* __restrict__ Wb,    // [128][256]
    const float* __restrict__ bias,
    unsigned short* __restrict__ outp,        // bf16 [n][128]
    int n) {
  __shared__ unsigned meanL[128][68];
  int lane = threadIdx.x & 63;
  int w = threadIdx.x >> 6;
  int blockBase = blockIdx.x * 128;

  // ---- phase A ----
  {
    int sub = lane & 15, eg = lane >> 4;
    for (int it = 0; it < 32; ++it) {
      int local = w * 32 + it;
      int node = blockBase + local;
      float acc[8];
#pragma unroll
      for (int k = 0; k < 8; ++k) acc[k] = 0.f;
      int dg = 0;
      if (node < n) {
        int r0 = rowStart[node];
        dg = deg[node];
        int r1 = r0 + dg;
        for (int base = r0; base < r1; base += 64) {
          int e = base + lane;
          int sv = (e < r1) ? srcs[e] : 0;
          int cnt = min(64, r1 - base);
          int j = 0;
          for (; j + 16 <= cnt; j += 16) {
            int s0 = __shfl(sv, j + eg);
            int s1 = __shfl(sv, j + 4 + eg);
            int s2 = __shfl(sv, j + 8 + eg);
            int s3 = __shfl(sv, j + 12 + eg);
            uint4 u0 = *(const uint4*)(in + (size_t)s0 * 64 + sub * 4);
            uint4 u1 = *(const uint4*)(in + (size_t)s1 * 64 + sub * 4);
            uint4 u2 = *(const uint4*)(in + (size_t)s2 * 64 + sub * 4);
            uint4 u3 = *(const uint4*)(in + (size_t)s3 * 64 + sub * 4);
            acc[0] += bflo(u0.x); acc[1] += bfhi(u0.x);
            acc[2] += bflo(u0.y); acc[3] += bfhi(u0.y);
            acc[4] += bflo(u0.z); acc[5] += bfhi(u0.z);
            acc[6] += bflo(u0.w); acc[7] += bfhi(u0.w);
            acc[0] += bflo(u1.x); acc[1] += bfhi(u1.x);
            acc[2] += bflo(u1.y); acc[3] += bfhi(u1.y);
            acc[4] += bflo(u1.z); acc[5] += bfhi(u1.z);
            acc[6] += bflo(u1.w); acc[7] += bfhi(u1.w);
            acc[0] += bflo(u2.x); acc[1] += bfhi(u2.x);
            acc[2] += bflo(u2.y); acc[3] += bfhi(u2.y);
            acc[4] += bflo(u2.z); acc[5] += bfhi(u2.z);
            acc[6] += bflo(u2.w); acc[7] += bfhi(u2.w);
            acc[0] += bflo(u3.x); acc[1] += bfhi(u3.x);
            acc[2] += bflo(u3.y); acc[3] += bfhi(u3.y);
            acc[4] += bflo(u3.z); acc[5] += bfhi(u3.z);
            acc[6] += bflo(u3.w); acc[7] += bfhi(u3.w);
          }
          for (; j + 8 <= cnt; j += 8) {
            int s0 = __shfl(sv, j + eg);
            int s1 = __shfl(sv, j + 4 + eg);
            uint4 u0 = *(const uint4*)(in + (size_t)s0 * 64 + sub * 4);
            uint4 u1 = *(const uint4*)(in + (size_t)s1 * 64 + sub * 4);
            acc[0] += bflo(u0.x); acc[1] += bfhi(u0.x);
            acc[2] += bflo(u0.y); acc[3] += bfhi(u0.y);
            acc[4] += bflo(u0.z); acc[5] += bfhi(u0.z);
            acc[6] += bflo(u0.w); acc[7] += bfhi(u0.w);
            acc[0] += bflo(u1.x); acc[1] += bfhi(u1.x);
            acc[2] += bflo(u1.y); acc[3] += bfhi(u1.y);
            acc[4] += bflo(u1.z); acc[5] += bfhi(u1.z);
            acc[6] += bflo(u1.w); acc[7] += bfhi(u1.w);
          }
          for (; j < cnt; j += 4) {
            int jj = j + eg;
            int s = __shfl(sv, jj);
            if (jj < cnt) {
              uint4 u = *(const uint4*)(in + (size_t)s * 64 + sub * 4);
              acc[0] += bflo(u.x); acc[1] += bfhi(u.x);
              acc[2] += bflo(u.y); acc[3] += bfhi(u.y);
              acc[4] += bflo(u.z); acc[5] += bfhi(u.z);
              acc[6] += bflo(u.w); acc[7] += bfhi(u.w);
            }
          }
        }
      }
#pragma unroll
      for (int k = 0; k < 8; ++k) {
        acc[k] += __shfl_down(acc[k], 32);
        acc[k] += __shfl_down(acc[k], 16);
      }
      if (eg == 0) {
        float sc = 1.0f / (float)max(dg, 1);
        uint4 o;
        o.x = (unsigned)f2bf(acc[0] * sc) | ((unsigned)f2bf(acc[1] * sc) << 16);
        o.y = (unsigned)f2bf(acc[2] * sc) | ((unsigned)f2bf(acc[3] * sc) << 16);
        o.z = (unsigned)f2bf(acc[4] * sc) | ((unsigned)f2bf(acc[5] * sc) << 16);
        o.w = (unsigned)f2bf(acc[6] * sc) | ((unsigned)f2bf(acc[7] * sc) << 16);
        *(uint4*)&meanL[local][sub * 4] = o;
      }
    }
  }
  __syncthreads();

  // ---- phase B: MFMA GEMM ----
  const unsigned short* selfB = (const unsigned short*)in;
  int wr = w & 1, wc = w >> 1;
  int nodeBase = blockBase + wr * 64;
  int colBase = wc * 64;
  int l15 = lane & 15, quad = lane >> 4;

  f32x4 acc[4][4];
#pragma unroll
  for (int t = 0; t < 4; ++t)
#pragma unroll
    for (int j = 0; j < 4; ++j) acc[t][j] = (f32x4){0.f, 0.f, 0.f, 0.f};

#pragma unroll
  for (int c = 0; c < 8; ++c) {
    int ko = (c & 3) * 32 + quad * 8;  // bf16-element offset
    short8 af[4], bfr[4];
    if (c < 4) {
#pragma unroll
      for (int t = 0; t < 4; ++t) {
        int row = min(nodeBase + t * 16 + l15, n - 1);
        af[t] = *(const short8*)(selfB + (size_t)row * 128 + ko);
      }
    } else {
#pragma unroll
      for (int t = 0; t < 4; ++t) {
        int lrow = wr * 64 + t * 16 + l15;
        af[t] = *(const short8*)((const unsigned short*)&meanL[lrow][0] + ko);
      }
    }
#pragma unroll
    for (int j = 0; j < 4; ++j) {
      int cn = colBase + j * 16 + l15;
      bfr[j] = *(const short8*)(Wb + (size_t)cn * 256 + c * 32 + quad * 8);
    }
#pragma unroll
    for (int t = 0; t < 4; ++t)
#pragma unroll
      for (int j = 0; j < 4; ++j)
        acc[t][j] = __builtin_amdgcn_mfma_f32_16x16x32_bf16(af[t], bfr[j], acc[t][j], 0, 0, 0);
  }

#pragma unroll
  for (int j = 0; j < 4; ++j) {
    int col = colBase + j * 16 + l15;
    float bv = bias[col];
#pragma unroll
    for (int t = 0; t < 4; ++t) {
#pragma unroll
      for (int r = 0; r < 4; ++r) {
        int row = nodeBase + t * 16 + quad * 4 + r;
        if (row < n) {
          float v = acc[t][j][r] + bv;
          if (RELU) v = fmaxf(v, 0.f);
          outp[(size_t)row * 128 + col] = f2bf(v);
        }
      }
    }
  }
}

// ---------------- layer-3 transform: y3 = h2 @ W3l.T (bf16 out, [n][64]) ----------------
__global__ __launch_bounds__(256, 4) void k_gemm_y3(
    const unsigned short* __restrict__ A,    // h2 [n][128]
    const unsigned short* __restrict__ Wb3,  // [64][256]; mean half at +128
    unsigned short* __restrict__ y3, int n) {
  int lane = threadIdx.x & 63;
  int w = threadIdx.x >> 6;
  int wr = w & 1, wc = w >> 1;
  int nodeBase = blockIdx.x * 128 + wr * 64;
  int colBase = wc * 32;
  int l15 = lane & 15, quad = lane >> 4;
  f32x4 acc[4][2];
#pragma unroll
  for (int t = 0; t < 4; ++t)
#pragma unroll
    for (int j = 0; j < 2; ++j) acc[t][j] = (f32x4){0.f, 0.f, 0.f, 0.f};
#pragma unroll
  for (int c = 0; c < 4; ++c) {
    int ko = c * 32 + quad * 8;
    short8 af[4], bfr[2];
#pragma unroll
    for (int t = 0; t < 4; ++t) {
      int row = min(nodeBase + t * 16 + l15, n - 1);
      af[t] = *(const short8*)(A + (size_t)row * 128 + ko);
    }
#pragma unroll
    for (int j = 0; j < 2; ++j) {
      int cn = colBase + j * 16 + l15;
      bfr[j] = *(const short8*)(Wb3 + (size_t)cn * 256 + 128 + c * 32 + quad * 8);
    }
#pragma unroll
    for (int t = 0; t < 4; ++t)
#pragma unroll
      for (int j = 0; j < 2; ++j)
        acc[t][j] = __builtin_amdgcn_mfma_f32_16x16x32_bf16(af[t], bfr[j], acc[t][j], 0, 0, 0);
  }
#pragma unroll
  for (int j = 0; j < 2; ++j) {
    int col = colBase + j * 16 + l15;
#pragma unroll
    for (int t = 0; t < 4; ++t) {
#pragma unroll
      for (int r = 0; r < 4; ++r) {
        int row = nodeBase + t * 16 + quad * 4 + r;
        if (row < n) y3[(size_t)row * 64 + col] = f2bf(acc[t][j][r]);
      }
    }
  }
}

// ---------------- layer-3 final: out = mean(y3) + h2 @ W3r.T + b3 (fp32 out) ----------------
__global__ __launch_bounds__(256, 3) void k_final(
    const unsigned* __restrict__ y3,          // [n][32] bf16x2 (128 B rows)
    const unsigned short* __restrict__ selfB, // h2 [n][128]
    const int* __restrict__ rowStart, const int* __restrict__ deg,
    const int* __restrict__ srcs,
    const unsigned short* __restrict__ Wb3,   // [64][256]; self half at +0
    const float* __restrict__ bias,
    float* __restrict__ outp, int n) {
  __shared__ float meanL[128][72];
  int lane = threadIdx.x & 63;
  int w = threadIdx.x >> 6;
  int blockBase = blockIdx.x * 128;

  // ---- phase A: aggregate y3 (64 ch) ----
  {
    int sub = lane & 7, eg = lane >> 3;  // 8 edge slots x 8 channel groups
    for (int it = 0; it < 32; ++it) {
      int local = w * 32 + it;
      int node = blockBase + local;
      float acc[8];
#pragma unroll
      for (int k = 0; k < 8; ++k) acc[k] = 0.f;
      int dg = 0;
      if (node < n) {
        int r0 = rowStart[node];
        dg = deg[node];
        int r1 = r0 + dg;
        for (int base = r0; base < r1; base += 64) {
          int e = base + lane;
          int sv = (e < r1) ? srcs[e] : 0;
          int cnt = min(64, r1 - base);
          int j = 0;
          for (; j + 16 <= cnt; j += 16) {
            int s0 = __shfl(sv, j + eg);
            int s1 = __shfl(sv, j + 8 + eg);
            uint4 u0 = *(const uint4*)(y3 + (size_t)s0 * 32 + sub * 4);
            uint4 u1 = *(const uint4*)(y3 + (size_t)s1 * 32 + sub * 4);
            acc[0] += bflo(u0.x); acc[1] += bfhi(u0.x);
            acc[2] += bflo(u0.y); acc[3] += bfhi(u0.y);
            acc[4] += bflo(u0.z); acc[5] += bfhi(u0.z);
            acc[6] += bflo(u0.w); acc[7] += bfhi(u0.w);
            acc[0] += bflo(u1.x); acc[1] += bfhi(u1.x);
            acc[2] += bflo(u1.y); acc[3] += bfhi(u1.y);
            acc[4] += bflo(u1.z); acc[5] += bfhi(u1.z);
            acc[6] += bflo(u1.w); acc[7] += bfhi(u1.w);
          }
          for (; j < cnt; j += 8) {
            int jj = j + eg;
            int s = __shfl(sv, jj);
            if (jj < cnt) {
              uint4 u = *(const uint4*)(y3 + (size_t)s * 32 + sub * 4);
              acc[0] += bflo(u.x); acc[1] += bfhi(u.x);
              acc[2] += bflo(u.y); acc[3] += bfhi(u.y);
              acc[4] += bflo(u.z); acc[5] += bfhi(u.z);
              acc[6] += bflo(u.w); acc[7] += bfhi(u.w);
            }
          }
        }
      }
#pragma unroll
      for (int k = 0; k < 8; ++k) {
        acc[k] += __shfl_down(acc[k], 32);
        acc[k] += __shfl_down(acc[k], 16);
        acc[k] += __shfl_down(acc[k], 8);
      }
      if (eg == 0) {
        float sc = 1.0f / (float)max(dg, 1);
        float4 o0 = make_float4(acc[0] * sc, acc[1] * sc, acc[2] * sc, acc[3] * sc);
        float4 o1 = make_float4(acc[4] * sc, acc[5] * sc, acc[6] * sc, acc[7] * sc);
        *(float4*)&meanL[local][sub * 8] = o0;
        *(float4*)&meanL[local][sub * 8 + 4] = o1;
      }
    }
  }
  __syncthreads();

  // ---- phase B: self MFMA (K=128) + mean + bias ----
  int wr = w & 1, wc = w >> 1;
  int nodeBase = blockBase + wr * 64;
  int colBase = wc * 32;
  int l15 = lane & 15, quad = lane >> 4;
  f32x4 acc[4][2];
#pragma unroll
  for (int t = 0; t < 4; ++t)
#pragma unroll
    for (int j = 0; j < 2; ++j) acc[t][j] = (f32x4){0.f, 0.f, 0.f, 0.f};
#pragma unroll
  for (int c = 0; c < 4; ++c) {
    int ko = c * 32 + quad * 8;
    short8 af[4], bfr[2];
#pragma unroll
    for (int t = 0; t < 4; ++t) {
      int row = min(nodeBase + t * 16 + l15, n - 1);
      af[t] = *(const short8*)(selfB + (size_t)row * 128 + ko);
    }
#pragma unroll
    for (int j = 0; j < 2; ++j) {
      int cn = colBase + j * 16 + l15;
      bfr[j] = *(const short8*)(Wb3 + (size_t)cn * 256 + c * 32 + quad * 8);
    }
#pragma unroll
    for (int t = 0; t < 4; ++t)
#pragma unroll
      for (int j = 0; j < 2; ++j)
        acc[t][j] = __builtin_amdgcn_mfma_f32_16x16x32_bf16(af[t], bfr[j], acc[t][j], 0, 0, 0);
  }
#pragma unroll
  for (int j = 0; j < 2; ++j) {
    int col = colBase + j * 16 + l15;
    float bv = bias[col];
#pragma unroll
    for (int t = 0; t < 4; ++t) {
#pragma unroll
      for (int r = 0; r < 4; ++r) {
        int lrow = wr * 64 + t * 16 + quad * 4 + r;
        int row = blockBase + lrow;
        if (row < n)
          outp[(size_t)row * 64 + col] = acc[t][j][r] + meanL[lrow][col] + bv;
      }
    }
  }
}

// ---------------- launch ----------------

extern "C" void kernel_launch(void* const* d_in, const int* in_sizes, int n_in,
                              void* d_out, int out_size, void* d_ws, size_t ws_size,
                              hipStream_t stream) {
  (void)n_in; (void)out_size; (void)ws_size;
  const float* x = (const float*)d_in[0];
  const void* edges = d_in[1];
  const float* W1l = (const float*)d_in[2];
  const float* W1r = (const float*)d_in[3];
  const float* b1 = (const float*)d_in[4];
  const float* W2l = (const float*)d_in[5];
  const float* W2r = (const float*)d_in[6];
  const float* b2 = (const float*)d_in[7];
  const float* W3l = (const float*)d_in[8];
  const float* W3r = (const float*)d_in[9];
  const float* b3 = (const float*)d_in[10];
  float* out = (float*)d_out;

  const int N = in_sizes[0] / 128;
  const int E = in_sizes[1] / 2;
  const int NB = (N + BSIZE - 1) >> BSHIFT;

  char* ws = (char*)d_ws;
  size_t off = 0;
  auto alloc = [&](size_t bytes) -> char* {
    char* p = ws + off;
    off = (off + bytes + 255) & ~(size_t)255;
    return p;
  };
  int* bucketCursor = (int*)alloc((size_t)NB * 4);
  unsigned* bucketed = (unsigned*)alloc((size_t)NB * CAP * 4);
  int* rowStart = (int*)alloc((size_t)N * 4);
  int* deg = (int*)alloc((size_t)N * 4);
  int* srcSorted = (int*)alloc((size_t)NB * CAP * 4);
  unsigned short* xb = (unsigned short*)alloc((size_t)N * 128 * 2);
  unsigned short* h1 = (unsigned short*)alloc((size_t)N * 128 * 2);
  unsigned short* h2 = (unsigned short*)alloc((size_t)N * 128 * 2);
  unsigned short* y3 = (unsigned short*)alloc((size_t)N * 64 * 2);
  unsigned short* Wb1 = (unsigned short*)alloc(128 * 256 * 2);
  unsigned short* Wb2 = (unsigned short*)alloc(128 * 256 * 2);
  unsigned short* Wb3 = (unsigned short*)alloc(64 * 256 * 2);

  int gE = NBLK(E, ECHUNK);
  int gSetup = NBLK(N * 64, 256) + 320 + gE;
  int gF = NBLK(N, 128);

  hipMemsetAsync(bucketCursor, 0, (size_t)NB * 4, stream);
  k_setup<<<gSetup, 256, 0, stream>>>(x, (unsigned*)xb, N,
                                      W1l, W1r, Wb1, W2l, W2r, Wb2, W3l, W3r, Wb3,
                                      edges, bucketCursor, bucketed, E, NB);
  k_csr<<<NB, 256, 0, stream>>>(bucketed, bucketCursor, rowStart, deg, srcSorted, N, NB);

  // layer 1 + 2 (fused aggregate + GEMM)
  k_fused128<true><<<gF, 256, 0, stream>>>((const unsigned*)xb, rowStart, deg, srcSorted,
                                           Wb1, b1, h1, N);
  k_fused128<true><<<gF, 256, 0, stream>>>((const unsigned*)h1, rowStart, deg, srcSorted,
                                           Wb2, b2, h2, N);
  // layer 3: transform-first, then aggregate + self-GEMM
  k_gemm_y3<<<gF, 256, 0, stream>>>(h2, Wb3, y3, N);
  k_final<<<gF, 256, 0, stream>>>((const unsigned*)y3, h2, rowStart, deg, srcSorted,
                                  Wb3, b3, out, N);
}

// Round 9
// 461.635 us; speedup vs baseline: 1.3160x; 1.3160x over previous
//
#include <hip/hip_runtime.h>
#include <hip/hip_bf16.h>
#include <cstddef>
#include <cstdint>

#define NBLK(n, b) (((n) + (b) - 1) / (b))

typedef __attribute__((ext_vector_type(8))) short short8;
typedef __attribute__((ext_vector_type(4))) float f32x4;

__device__ inline unsigned short f2bf(float f) {
  union { float f; unsigned u; } v; v.f = f;
  unsigned u = v.u;
  u += 0x7FFFu + ((u >> 16) & 1u);  // RNE
  return (unsigned short)(u >> 16);
}
__device__ inline float bflo(unsigned u) { union { unsigned u; float f; } v; v.u = u << 16; return v.f; }
__device__ inline float bfhi(unsigned u) { union { unsigned u; float f; } v; v.u = u & 0xFFFF0000u; return v.f; }

// CSR bucket sort: buckets of 512 nodes; node ids < 2^17 (N=100K).
// key = src | (localDst << 17) fits u32. Fixed-capacity padded buckets.
#define BSHIFT 9
#define BSIZE 512
#define CAPSHIFT 14
#define CAP 16384
#define ECHUNK 2048

// ---------------- cast x -> bf16, prep packed weights ----------------
__global__ __launch_bounds__(256) void k_cast(
    const float* __restrict__ x, unsigned* __restrict__ xb, int N,
    const float* __restrict__ W1l, const float* __restrict__ W1r, unsigned short* __restrict__ Wb1,
    const float* __restrict__ W2l, const float* __restrict__ W2r, unsigned short* __restrict__ Wb2,
    const float* __restrict__ W3l, const float* __restrict__ W3r, unsigned short* __restrict__ Wb3) {
  int t = threadIdx.x;
  int b = blockIdx.x;
  int gCast = (N * 64 + 255) >> 8;
  if (b < gCast) {
    int i = b * 256 + t;
    if (i < N * 64) {
      float2 v = *(const float2*)(x + (size_t)i * 2);
      xb[i] = (unsigned)f2bf(v.x) | ((unsigned)f2bf(v.y) << 16);
    }
    return;
  }
  b -= gCast;
  int ii = b * 256 + t;
  const float *Wl, *Wr; unsigned short* Wb;
  if (ii < 128 * 256) { Wl = W1l; Wr = W1r; Wb = Wb1; }
  else if (ii < 256 * 256) { Wl = W2l; Wr = W2r; Wb = Wb2; ii -= 128 * 256; }
  else { Wl = W3l; Wr = W3r; Wb = Wb3; ii -= 256 * 256; }
  int nrow = ii >> 8, k = ii & 255;
  float v = (k < 128) ? Wr[nrow * 128 + k] : Wl[nrow * 128 + (k - 128)];
  Wb[ii] = f2bf(v);
}

// ---------------- edge scatter into padded buckets ----------------
__global__ __launch_bounds__(256) void k_scatter(
    const void* __restrict__ edges, int* __restrict__ bucketCursor,
    unsigned* __restrict__ bucketed, int E, int NB) {
  __shared__ int h[1024];
  __shared__ int base2[1024];
  int t = threadIdx.x;
  int b = blockIdx.x;

  const unsigned* e32 = (const unsigned*)edges;
  int is64 = 1;
#pragma unroll
  for (int i = 0; i < 16; ++i)
    if (e32[2 * i + 1] != 0u) is64 = 0;

  for (int i = t; i < NB; i += 256) h[i] = 0;
  __syncthreads();
  int base_e = b * ECHUNK;
  unsigned key[8];
  int bkt[8];
#pragma unroll
  for (int k = 0; k < 8; ++k) {
    int e = base_e + k * 256 + t;
    bkt[k] = -1;
    if (e < E) {
      int s, d;
      if (is64) {
        s = (int)((const long long*)edges)[e];
        d = (int)((const long long*)edges)[(size_t)E + e];
      } else {
        s = ((const int*)edges)[e];
        d = ((const int*)edges)[(size_t)E + e];
      }
      bkt[k] = d >> BSHIFT;
      key[k] = (unsigned)s | ((unsigned)(d & (BSIZE - 1)) << 17);
      atomicAdd(&h[bkt[k]], 1);
    }
  }
  __syncthreads();
  for (int i = t; i < NB; i += 256) {
    int c = h[i];
    base2[i] = c ? atomicAdd(&bucketCursor[i], c) : 0;
    h[i] = 0;
  }
  __syncthreads();
#pragma unroll
  for (int k = 0; k < 8; ++k) {
    if (bkt[k] >= 0) {
      int r = atomicAdd(&h[bkt[k]], 1);
      int pos = base2[bkt[k]] + r;
      if (pos < CAP)
        bucketed[((size_t)bkt[k] << CAPSHIFT) + pos] = key[k];
    }
  }
}

// ---------------- per-bucket CSR: rowStart + deg + srcSorted (padded layout) ----------------
__global__ __launch_bounds__(256) void k_csr(const unsigned* __restrict__ bucketed,
                                             const int* __restrict__ bucketCursor,
                                             int* __restrict__ rowStart, int* __restrict__ deg,
                                             int* __restrict__ srcSorted, int N, int NB) {
  __shared__ int h[512];
  __shared__ int excl[512];
  __shared__ int sd[256];
  int b = blockIdx.x;
  int t = threadIdx.x;
  int nodeBase = b << BSHIFT;
  int nNode = min(BSIZE, N - nodeBase);
  int cnt = min(bucketCursor[b], CAP);
  size_t s0 = (size_t)b << CAPSHIFT;
  h[t * 2] = 0; h[t * 2 + 1] = 0;
  __syncthreads();
  for (int i = t; i < cnt; i += 256) {
    int ld = bucketed[s0 + i] >> 17;
    atomicAdd(&h[ld], 1);
  }
  __syncthreads();
  int a0 = h[t * 2], a1 = h[t * 2 + 1];
  int s = a0 + a1;
  sd[t] = s;
  __syncthreads();
  for (int off = 1; off < 256; off <<= 1) {
    int xv = (t >= off) ? sd[t - off] : 0;
    __syncthreads();
    sd[t] += xv;
    __syncthreads();
  }
  int run = sd[t] - s;
  excl[t * 2] = run;
  excl[t * 2 + 1] = run + a0;
  if (t * 2 < nNode) {
    rowStart[nodeBase + t * 2] = (int)s0 + run;
    deg[nodeBase + t * 2] = a0;
  }
  if (t * 2 + 1 < nNode) {
    rowStart[nodeBase + t * 2 + 1] = (int)s0 + run + a0;
    deg[nodeBase + t * 2 + 1] = a1;
  }
  h[t * 2] = 0; h[t * 2 + 1] = 0;
  __syncthreads();
  for (int i = t; i < cnt; i += 256) {
    unsigned u = bucketed[s0 + i];
    int ld = u >> 17;
    int r = atomicAdd(&h[ld], 1);
    srcSorted[s0 + excl[ld] + r] = (int)(u & 0x1FFFFu);
  }
}

// ---------------- aggregation: mean over in-neighbors, 256B rows (bf16) ----------------
// One wave per node. Lane = (eg in [0,4)) x (sub in [0,16)); unroll x4.
__global__ void k_aggregate(const unsigned* __restrict__ in, const int* __restrict__ rowStart,
                            const int* __restrict__ deg, const int* __restrict__ srcs,
                            unsigned* __restrict__ mean, int n) {
  int lane = threadIdx.x & 63;
  int w = threadIdx.x >> 6;
  int node = blockIdx.x * 4 + w;
  if (node >= n) return;
  int r0 = rowStart[node];
  int dg = deg[node];
  int r1 = r0 + dg;
  int sub = lane & 15;
  int eg = lane >> 4;
  float acc[8];
#pragma unroll
  for (int k = 0; k < 8; ++k) acc[k] = 0.f;

  for (int base = r0; base < r1; base += 64) {
    int e = base + lane;
    int sv = (e < r1) ? srcs[e] : 0;
    int cnt = min(64, r1 - base);
    int j = 0;
    for (; j + 16 <= cnt; j += 16) {
      int s0 = __shfl(sv, j + eg);
      int s1 = __shfl(sv, j + 4 + eg);
      int s2 = __shfl(sv, j + 8 + eg);
      int s3 = __shfl(sv, j + 12 + eg);
      uint4 u0 = *(const uint4*)(in + (size_t)s0 * 64 + sub * 4);
      uint4 u1 = *(const uint4*)(in + (size_t)s1 * 64 + sub * 4);
      uint4 u2 = *(const uint4*)(in + (size_t)s2 * 64 + sub * 4);
      uint4 u3 = *(const uint4*)(in + (size_t)s3 * 64 + sub * 4);
      acc[0] += bflo(u0.x); acc[1] += bfhi(u0.x);
      acc[2] += bflo(u0.y); acc[3] += bfhi(u0.y);
      acc[4] += bflo(u0.z); acc[5] += bfhi(u0.z);
      acc[6] += bflo(u0.w); acc[7] += bfhi(u0.w);
      acc[0] += bflo(u1.x); acc[1] += bfhi(u1.x);
      acc[2] += bflo(u1.y); acc[3] += bfhi(u1.y);
      acc[4] += bflo(u1.z); acc[5] += bfhi(u1.z);
      acc[6] += bflo(u1.w); acc[7] += bfhi(u1.w);
      acc[0] += bflo(u2.x); acc[1] += bfhi(u2.x);
      acc[2] += bflo(u2.y); acc[3] += bfhi(u2.y);
      acc[4] += bflo(u2.z); acc[5] += bfhi(u2.z);
      acc[6] += bflo(u2.w); acc[7] += bfhi(u2.w);
      acc[0] += bflo(u3.x); acc[1] += bfhi(u3.x);
      acc[2] += bflo(u3.y); acc[3] += bfhi(u3.y);
      acc[4] += bflo(u3.z); acc[5] += bfhi(u3.z);
      acc[6] += bflo(u3.w); acc[7] += bfhi(u3.w);
    }
    for (; j + 8 <= cnt; j += 8) {
      int s0 = __shfl(sv, j + eg);
      int s1 = __shfl(sv, j + 4 + eg);
      uint4 u0 = *(const uint4*)(in + (size_t)s0 * 64 + sub * 4);
      uint4 u1 = *(const uint4*)(in + (size_t)s1 * 64 + sub * 4);
      acc[0] += bflo(u0.x); acc[1] += bfhi(u0.x);
      acc[2] += bflo(u0.y); acc[3] += bfhi(u0.y);
      acc[4] += bflo(u0.z); acc[5] += bfhi(u0.z);
      acc[6] += bflo(u0.w); acc[7] += bfhi(u0.w);
      acc[0] += bflo(u1.x); acc[1] += bfhi(u1.x);
      acc[2] += bflo(u1.y); acc[3] += bfhi(u1.y);
      acc[4] += bflo(u1.z); acc[5] += bfhi(u1.z);
      acc[6] += bflo(u1.w); acc[7] += bfhi(u1.w);
    }
    for (; j < cnt; j += 4) {
      int jj = j + eg;
      int s = __shfl(sv, jj);
      if (jj < cnt) {
        uint4 u = *(const uint4*)(in + (size_t)s * 64 + sub * 4);
        acc[0] += bflo(u.x); acc[1] += bfhi(u.x);
        acc[2] += bflo(u.y); acc[3] += bfhi(u.y);
        acc[4] += bflo(u.z); acc[5] += bfhi(u.z);
        acc[6] += bflo(u.w); acc[7] += bfhi(u.w);
      }
    }
  }

#pragma unroll
  for (int k = 0; k < 8; ++k) {
    acc[k] += __shfl_down(acc[k], 32);
    acc[k] += __shfl_down(acc[k], 16);
  }
  if (eg == 0) {
    float sc = 1.0f / (float)max(dg, 1);
    uint4 o;
    o.x = (unsigned)f2bf(acc[0] * sc) | ((unsigned)f2bf(acc[1] * sc) << 16);
    o.y = (unsigned)f2bf(acc[2] * sc) | ((unsigned)f2bf(acc[3] * sc) << 16);
    o.z = (unsigned)f2bf(acc[4] * sc) | ((unsigned)f2bf(acc[5] * sc) << 16);
    o.w = (unsigned)f2bf(acc[6] * sc) | ((unsigned)f2bf(acc[7] * sc) << 16);
    *(uint4*)(mean + (size_t)node * 64 + sub * 4) = o;
  }
}

// ---------------- MFMA GEMM: out = self@Wr.T + mean@Wl.T + b (layers 1-2) ----------------
template <int H, bool RELU, bool BF16OUT>
__global__ __launch_bounds__(256) void k_gemm(
    const unsigned short* __restrict__ selfB, const unsigned short* __restrict__ meanB,
    const unsigned short* __restrict__ Wb, const float* __restrict__ bias,
    void* __restrict__ outp, int n) {
  constexpr int TN = H / 32;
  int lane = threadIdx.x & 63;
  int w = threadIdx.x >> 6;
  int wr = w & 1, wc = w >> 1;
  int nodeBase = blockIdx.x * 128 + wr * 64;
  int colBase = wc * (H / 2);
  int l15 = lane & 15, quad = lane >> 4;

  f32x4 acc[4][TN];
#pragma unroll
  for (int t = 0; t < 4; ++t)
#pragma unroll
    for (int j = 0; j < TN; ++j) acc[t][j] = (f32x4){0.f, 0.f, 0.f, 0.f};

#pragma unroll
  for (int c = 0; c < 8; ++c) {
    const unsigned short* A = (c < 4) ? selfB : meanB;
    int ko = (c & 3) * 32 + quad * 8;
    short8 af[4], bfr[TN];
#pragma unroll
    for (int t = 0; t < 4; ++t) {
      int row = min(nodeBase + t * 16 + l15, n - 1);
      af[t] = *(const short8*)(A + (size_t)row * 128 + ko);
    }
#pragma unroll
    for (int j = 0; j < TN; ++j) {
      int cn = colBase + j * 16 + l15;
      bfr[j] = *(const short8*)(Wb + (size_t)cn * 256 + c * 32 + quad * 8);
    }
#pragma unroll
    for (int t = 0; t < 4; ++t)
#pragma unroll
      for (int j = 0; j < TN; ++j)
        acc[t][j] = __builtin_amdgcn_mfma_f32_16x16x32_bf16(af[t], bfr[j], acc[t][j], 0, 0, 0);
  }

#pragma unroll
  for (int j = 0; j < TN; ++j) {
    int col = colBase + j * 16 + l15;
    float bv = bias[col];
#pragma unroll
    for (int t = 0; t < 4; ++t) {
#pragma unroll
      for (int r = 0; r < 4; ++r) {
        int row = nodeBase + t * 16 + quad * 4 + r;
        if (row < n) {
          float v = acc[t][j][r] + bv;
          if (RELU) v = fmaxf(v, 0.f);
          if (BF16OUT) ((unsigned short*)outp)[(size_t)row * H + col] = f2bf(v);
          else ((float*)outp)[(size_t)row * H + col] = v;
        }
      }
    }
  }
}

// ---------------- layer-3 combined transform: out = h2@W3r.T + b3 (fp32); y3 = h2@W3l.T (bf16) ----------------
// 4 waves: wr = node half, wc = task (0 -> out/self, 1 -> y3/mean-weight).
__global__ __launch_bounds__(256) void k_gemm3_both(
    const unsigned short* __restrict__ A,    // h2 [n][128]
    const unsigned short* __restrict__ Wb3,  // [64][256]: self half +0, mean half +128
    const float* __restrict__ bias,
    float* __restrict__ outp, unsigned short* __restrict__ y3, int n) {
  int lane = threadIdx.x & 63;
  int w = threadIdx.x >> 6;
  int wr = w & 1, wc = w >> 1;
  int nodeBase = blockIdx.x * 128 + wr * 64;
  int l15 = lane & 15, quad = lane >> 4;
  int woff = wc ? 128 : 0;
  f32x4 acc[4][4];
#pragma unroll
  for (int t = 0; t < 4; ++t)
#pragma unroll
    for (int j = 0; j < 4; ++j) acc[t][j] = (f32x4){0.f, 0.f, 0.f, 0.f};
#pragma unroll
  for (int c = 0; c < 4; ++c) {
    int ko = c * 32 + quad * 8;
    short8 af[4], bfr[4];
#pragma unroll
    for (int t = 0; t < 4; ++t) {
      int row = min(nodeBase + t * 16 + l15, n - 1);
      af[t] = *(const short8*)(A + (size_t)row * 128 + ko);
    }
#pragma unroll
    for (int j = 0; j < 4; ++j) {
      int cn = j * 16 + l15;
      bfr[j] = *(const short8*)(Wb3 + (size_t)cn * 256 + woff + c * 32 + quad * 8);
    }
#pragma unroll
    for (int t = 0; t < 4; ++t)
#pragma unroll
      for (int j = 0; j < 4; ++j)
        acc[t][j] = __builtin_amdgcn_mfma_f32_16x16x32_bf16(af[t], bfr[j], acc[t][j], 0, 0, 0);
  }
#pragma unroll
  for (int j = 0; j < 4; ++j) {
    int col = j * 16 + l15;
    float bv = wc ? 0.f : bias[col];
#pragma unroll
    for (int t = 0; t < 4; ++t) {
#pragma unroll
      for (int r = 0; r < 4; ++r) {
        int row = nodeBase + t * 16 + quad * 4 + r;
        if (row < n) {
          float v = acc[t][j][r] + bv;
          if (wc) y3[(size_t)row * 64 + col] = f2bf(v);
          else outp[(size_t)row * 64 + col] = v;
        }
      }
    }
  }
}

// ---------------- layer-3 aggregate: out += mean(y3 over in-neighbors) ----------------
// One wave per node; y3 rows are 128 B. Lane = (eg in [0,8)) x (sub in [0,8)).
__global__ void k_agg64_add(const unsigned* __restrict__ y3, const int* __restrict__ rowStart,
                            const int* __restrict__ deg, const int* __restrict__ srcs,
                            float* __restrict__ outp, int n) {
  int lane = threadIdx.x & 63;
  int w = threadIdx.x >> 6;
  int node = blockIdx.x * 4 + w;
  if (node >= n) return;
  int dg = deg[node];
  if (dg == 0) return;
  int r0 = rowStart[node];
  int r1 = r0 + dg;
  int sub = lane & 7;  // 8 channel groups x 16 B
  int eg = lane >> 3;  // 8 edge slots
  float acc[8];
#pragma unroll
  for (int k = 0; k < 8; ++k) acc[k] = 0.f;

  for (int base = r0; base < r1; base += 64) {
    int e = base + lane;
    int sv = (e < r1) ? srcs[e] : 0;
    int cnt = min(64, r1 - base);
    int j = 0;
    for (; j + 16 <= cnt; j += 16) {
      int s0 = __shfl(sv, j + eg);
      int s1 = __shfl(sv, j + 8 + eg);
      uint4 u0 = *(const uint4*)(y3 + (size_t)s0 * 32 + sub * 4);
      uint4 u1 = *(const uint4*)(y3 + (size_t)s1 * 32 + sub * 4);
      acc[0] += bflo(u0.x); acc[1] += bfhi(u0.x);
      acc[2] += bflo(u0.y); acc[3] += bfhi(u0.y);
      acc[4] += bflo(u0.z); acc[5] += bfhi(u0.z);
      acc[6] += bflo(u0.w); acc[7] += bfhi(u0.w);
      acc[0] += bflo(u1.x); acc[1] += bfhi(u1.x);
      acc[2] += bflo(u1.y); acc[3] += bfhi(u1.y);
      acc[4] += bflo(u1.z); acc[5] += bfhi(u1.z);
      acc[6] += bflo(u1.w); acc[7] += bfhi(u1.w);
    }
    for (; j < cnt; j += 8) {
      int jj = j + eg;
      int s = __shfl(sv, jj);
      if (jj < cnt) {
        uint4 u = *(const uint4*)(y3 + (size_t)s * 32 + sub * 4);
        acc[0] += bflo(u.x); acc[1] += bfhi(u.x);
        acc[2] += bflo(u.y); acc[3] += bfhi(u.y);
        acc[4] += bflo(u.z); acc[5] += bfhi(u.z);
        acc[6] += bflo(u.w); acc[7] += bfhi(u.w);
      }
    }
  }

#pragma unroll
  for (int k = 0; k < 8; ++k) {
    acc[k] += __shfl_down(acc[k], 32);
    acc[k] += __shfl_down(acc[k], 16);
    acc[k] += __shfl_down(acc[k], 8);
  }
  if (eg == 0) {
    float sc = 1.0f / (float)dg;
    float* op = outp + (size_t)node * 64 + sub * 8;
    float4 a = *(float4*)op;
    float4 b = *(float4*)(op + 4);
    a.x += acc[0] * sc; a.y += acc[1] * sc; a.z += acc[2] * sc; a.w += acc[3] * sc;
    b.x += acc[4] * sc; b.y += acc[5] * sc; b.z += acc[6] * sc; b.w += acc[7] * sc;
    *(float4*)op = a;
    *(float4*)(op + 4) = b;
  }
}

// ---------------- launch ----------------

extern "C" void kernel_launch(void* const* d_in, const int* in_sizes, int n_in,
                              void* d_out, int out_size, void* d_ws, size_t ws_size,
                              hipStream_t stream) {
  (void)n_in; (void)out_size; (void)ws_size;
  const float* x = (const float*)d_in[0];
  const void* edges = d_in[1];
  const float* W1l = (const float*)d_in[2];
  const float* W1r = (const float*)d_in[3];
  const float* b1 = (const float*)d_in[4];
  const float* W2l = (const float*)d_in[5];
  const float* W2r = (const float*)d_in[6];
  const float* b2 = (const float*)d_in[7];
  const float* W3l = (const float*)d_in[8];
  const float* W3r = (const float*)d_in[9];
  const float* b3 = (const float*)d_in[10];
  float* out = (float*)d_out;

  const int N = in_sizes[0] / 128;
  const int E = in_sizes[1] / 2;
  const int NB = (N + BSIZE - 1) >> BSHIFT;

  char* ws = (char*)d_ws;
  size_t off = 0;
  auto alloc = [&](size_t bytes) -> char* {
    char* p = ws + off;
    off = (off + bytes + 255) & ~(size_t)255;
    return p;
  };
  int* bucketCursor = (int*)alloc((size_t)NB * 4);
  unsigned* bucketed = (unsigned*)alloc((size_t)NB * CAP * 4);
  int* rowStart = (int*)alloc((size_t)N * 4);
  int* deg = (int*)alloc((size_t)N * 4);
  int* srcSorted = (int*)alloc((size_t)NB * CAP * 4);
  unsigned short* xb = (unsigned short*)alloc((size_t)N * 128 * 2);
  unsigned short* mean = (unsigned short*)alloc((size_t)N * 128 * 2);
  unsigned short* h1 = (unsigned short*)alloc((size_t)N * 128 * 2);
  unsigned short* h2 = (unsigned short*)alloc((size_t)N * 128 * 2);
  unsigned short* y3 = (unsigned short*)alloc((size_t)N * 64 * 2);
  unsigned short* Wb1 = (unsigned short*)alloc(128 * 256 * 2);
  unsigned short* Wb2 = (unsigned short*)alloc(128 * 256 * 2);
  unsigned short* Wb3 = (unsigned short*)alloc(64 * 256 * 2);

  int gCast = NBLK(N * 64, 256) + 320;
  int gE = NBLK(E, ECHUNK);
  int gAgg = NBLK(N, 4);
  int gGemm = NBLK(N, 128);

  hipMemsetAsync(bucketCursor, 0, (size_t)NB * 4, stream);
  k_cast<<<gCast, 256, 0, stream>>>(x, (unsigned*)xb, N,
                                    W1l, W1r, Wb1, W2l, W2r, Wb2, W3l, W3r, Wb3);
  k_scatter<<<gE, 256, 0, stream>>>(edges, bucketCursor, bucketed, E, NB);
  k_csr<<<NB, 256, 0, stream>>>(bucketed, bucketCursor, rowStart, deg, srcSorted, N, NB);

  // layer 1
  k_aggregate<<<gAgg, 256, 0, stream>>>((const unsigned*)xb, rowStart, deg, srcSorted, (unsigned*)mean, N);
  k_gemm<128, true, true><<<gGemm, 256, 0, stream>>>(xb, mean, Wb1, b1, h1, N);
  // layer 2
  k_aggregate<<<gAgg, 256, 0, stream>>>((const unsigned*)h1, rowStart, deg, srcSorted, (unsigned*)mean, N);
  k_gemm<128, true, true><<<gGemm, 256, 0, stream>>>(h1, mean, Wb2, b2, h2, N);
  // layer 3: transform-first
  k_gemm3_both<<<gGemm, 256, 0, stream>>>(h2, Wb3, b3, out, y3, N);
  k_agg64_add<<<gAgg, 256, 0, stream>>>((const unsigned*)y3, rowStart, deg, srcSorted, out, N);
}